// Round 1
// baseline (425.565 us; speedup 1.0000x reference)
//
#include <hip/hip_runtime.h>

// Problem constants (fixed by the reference)
constexpr int B_  = 4;
constexpr int S_  = 512;
constexpr int D_  = 256;
constexpr int HW_ = 4096;   // 64*64 spatial
constexpr int NH_ = 8;
constexpr int HD_ = 32;     // head dim

// ---------------------------------------------------------------------------
// GEMM with fused bias: C[m][n] = sum_k A[m][k] * W[n][k] + bias[n]
//   TRANS_A=false: A is row-major MxK.
//   TRANS_A=true : logical A[m][k] = KV[b*K*HW_ + k*HW_ + hw], m = b*HW_+hw
//                  (key_value consumed transposed in place, coalesced over hw)
// 64x64x16 tile, 256 threads, 4x4 microtile per thread.
// ---------------------------------------------------------------------------
template<bool TRANS_A>
__global__ __launch_bounds__(256)
void gemm_bias(const float* __restrict__ A, const float* __restrict__ W,
               const float* __restrict__ bias, float* __restrict__ C,
               int M, int N, int K)
{
  constexpr int BM = 64, BN = 64, BK = 16;
  // rows padded to 68 floats: 272B rows keep float4 alignment, ~2-way banks max
  __shared__ __align__(16) float As[BK][BM + 4];
  __shared__ __align__(16) float Ws[BK][BN + 4];

  const int tid = threadIdx.x;
  const int tm = tid >> 4, tn = tid & 15;
  const int m0 = blockIdx.x * BM, n0 = blockIdx.y * BN;

  float acc[4][4] = {};

  for (int k0 = 0; k0 < K; k0 += BK) {
    { // stage W tile (BN x BK) transposed into Ws[k][n]
      const int n = tid >> 2, kq = tid & 3;
      const float4 w = *(const float4*)&W[(size_t)(n0 + n) * K + k0 + kq * 4];
      Ws[kq*4+0][n] = w.x; Ws[kq*4+1][n] = w.y;
      Ws[kq*4+2][n] = w.z; Ws[kq*4+3][n] = w.w;
    }
    if (TRANS_A) {
      // coalesced along hw (=m); conflict-free LDS stores (addr = 68k + m)
      const int b = m0 / HW_, hw0 = m0 % HW_;
      const float* Ab = A + (size_t)b * K * HW_ + hw0;
      #pragma unroll
      for (int i = 0; i < 4; ++i) {
        const int idx = tid + i * 256;
        const int m = idx & 63, k = idx >> 6;
        As[k][m] = Ab[(size_t)(k0 + k) * HW_ + m];
      }
    } else {
      const int m = tid >> 2, kq = tid & 3;
      const float4 a = *(const float4*)&A[(size_t)(m0 + m) * K + k0 + kq * 4];
      As[kq*4+0][m] = a.x; As[kq*4+1][m] = a.y;
      As[kq*4+2][m] = a.z; As[kq*4+3][m] = a.w;
    }
    __syncthreads();

    #pragma unroll
    for (int k = 0; k < BK; ++k) {
      const float4 a4 = *(const float4*)&As[k][tm * 4];
      const float4 w4 = *(const float4*)&Ws[k][tn * 4];
      const float av[4] = {a4.x, a4.y, a4.z, a4.w};
      const float wv[4] = {w4.x, w4.y, w4.z, w4.w};
      #pragma unroll
      for (int i = 0; i < 4; ++i)
        #pragma unroll
        for (int j = 0; j < 4; ++j)
          acc[i][j] = fmaf(av[i], wv[j], acc[i][j]);
    }
    __syncthreads();
  }

  #pragma unroll
  for (int i = 0; i < 4; ++i) {
    const int gm = m0 + tm * 4 + i;
    const int gn = n0 + tn * 4;
    float4 o;
    o.x = acc[i][0] + bias[gn + 0];
    o.y = acc[i][1] + bias[gn + 1];
    o.z = acc[i][2] + bias[gn + 2];
    o.w = acc[i][3] + bias[gn + 3];
    *(float4*)&C[(size_t)gm * N + gn] = o;
  }
}

// ---------------------------------------------------------------------------
// Fused flash-style attention (fp32). One block = (b, head, 64-row q-tile).
// Online softmax; rows are distributed across 16 consecutive lanes (tn) so
// row reductions are __shfl_xor width-16. P goes through padded LDS for PV.
// ---------------------------------------------------------------------------
__global__ __launch_bounds__(256)
void attn_fused(const float* __restrict__ Qp, const float* __restrict__ Kp,
                const float* __restrict__ Vp, float* __restrict__ Op)
{
  constexpr int QT = 64, KT = 64;
  __shared__ __align__(16) float Qs[HD_][QT + 4];  // transposed: Qs[d][m]
  __shared__ __align__(16) float Ks[HD_][KT + 4];  // transposed: Ks[d][n]
  __shared__ __align__(16) float Vs[KT][HD_ + 4];  // row-major: Vs[n][d]
  __shared__ __align__(16) float Ps[QT][KT + 4];

  const int tid = threadIdx.x;
  const int tm = tid >> 4, tn = tid & 15;
  const int bid = blockIdx.x;
  const int qt = bid & 7;          // S_/QT = 8 q-tiles
  const int h  = (bid >> 3) & 7;   // NH_ = 8
  const int b  = bid >> 6;
  const int q0 = qt * QT;
  const float scale = 0.1767766952966369f; // 1/sqrt(32), folded into Q

  // Stage Q tile, scaled + transposed
  #pragma unroll
  for (int i = 0; i < 2; ++i) {
    const int idx = tid + i * 256;
    const int m = idx >> 3, f = idx & 7;
    const float4 q = *(const float4*)&Qp[(size_t)(b * S_ + q0 + m) * D_ + h * HD_ + f * 4];
    Qs[f*4+0][m] = q.x * scale; Qs[f*4+1][m] = q.y * scale;
    Qs[f*4+2][m] = q.z * scale; Qs[f*4+3][m] = q.w * scale;
  }

  float Mx[4], Ls[4], Oa[4][2];
  #pragma unroll
  for (int i = 0; i < 4; ++i) { Mx[i] = -1e30f; Ls[i] = 0.f; Oa[i][0] = 0.f; Oa[i][1] = 0.f; }

  for (int t = 0; t < HW_ / KT; ++t) {
    // Stage K (transposed) and V tiles
    #pragma unroll
    for (int i = 0; i < 2; ++i) {
      const int idx = tid + i * 256;
      const int n = idx >> 3, f = idx & 7;
      const size_t row = (size_t)(b * HW_ + t * KT + n) * D_ + h * HD_ + f * 4;
      const float4 kk = *(const float4*)&Kp[row];
      Ks[f*4+0][n] = kk.x; Ks[f*4+1][n] = kk.y;
      Ks[f*4+2][n] = kk.z; Ks[f*4+3][n] = kk.w;
      const float4 vv = *(const float4*)&Vp[row];
      Vs[n][f*4+0] = vv.x; Vs[n][f*4+1] = vv.y;
      Vs[n][f*4+2] = vv.z; Vs[n][f*4+3] = vv.w;
    }
    __syncthreads();

    // scores: s[i][j] = q_(4tm+i) . k_(4tn+j)   (Q pre-scaled)
    float s[4][4] = {};
    #pragma unroll
    for (int d = 0; d < HD_; ++d) {
      const float4 qa = *(const float4*)&Qs[d][tm * 4];
      const float4 kb = *(const float4*)&Ks[d][tn * 4];
      const float av[4] = {qa.x, qa.y, qa.z, qa.w};
      const float kv[4] = {kb.x, kb.y, kb.z, kb.w};
      #pragma unroll
      for (int i = 0; i < 4; ++i)
        #pragma unroll
        for (int j = 0; j < 4; ++j)
          s[i][j] = fmaf(av[i], kv[j], s[i][j]);
    }

    // online softmax per row
    #pragma unroll
    for (int i = 0; i < 4; ++i) {
      float rm = fmaxf(fmaxf(s[i][0], s[i][1]), fmaxf(s[i][2], s[i][3]));
      #pragma unroll
      for (int off = 1; off < 16; off <<= 1)
        rm = fmaxf(rm, __shfl_xor(rm, off, 16));
      const float nm = fmaxf(Mx[i], rm);
      const float fr = __expf(Mx[i] - nm);  // Mx=-1e30 sentinel -> fr=0 first tile
      Mx[i] = nm;
      const float p0 = __expf(s[i][0] - nm);
      const float p1 = __expf(s[i][1] - nm);
      const float p2 = __expf(s[i][2] - nm);
      const float p3 = __expf(s[i][3] - nm);
      *(float4*)&Ps[tm * 4 + i][tn * 4] = make_float4(p0, p1, p2, p3);
      float rs = p0 + p1 + p2 + p3;
      #pragma unroll
      for (int off = 1; off < 16; off <<= 1)
        rs += __shfl_xor(rs, off, 16);
      Ls[i] = Ls[i] * fr + rs;
      Oa[i][0] *= fr; Oa[i][1] *= fr;
    }
    __syncthreads();

    // PV: Oa[i][c] += sum_n P[4tm+i][n] * V[n][2tn+c]
    #pragma unroll
    for (int n4 = 0; n4 < KT / 4; ++n4) {
      float4 p[4];
      #pragma unroll
      for (int i = 0; i < 4; ++i) p[i] = *(const float4*)&Ps[tm * 4 + i][n4 * 4];
      float2 v[4];
      #pragma unroll
      for (int c = 0; c < 4; ++c) v[c] = *(const float2*)&Vs[n4 * 4 + c][tn * 2];
      #pragma unroll
      for (int i = 0; i < 4; ++i) {
        Oa[i][0] += p[i].x * v[0].x + p[i].y * v[1].x + p[i].z * v[2].x + p[i].w * v[3].x;
        Oa[i][1] += p[i].x * v[0].y + p[i].y * v[1].y + p[i].z * v[2].y + p[i].w * v[3].y;
      }
    }
    __syncthreads();
  }

  // normalize + write (B, S, nH*hd) so the O-projection reads it row-major
  #pragma unroll
  for (int i = 0; i < 4; ++i) {
    const float inv = 1.0f / Ls[i];
    float2 o; o.x = Oa[i][0] * inv; o.y = Oa[i][1] * inv;
    *(float2*)&Op[(size_t)(b * S_ + q0 + tm * 4 + i) * D_ + h * HD_ + tn * 2] = o;
  }
}

// ---------------------------------------------------------------------------
extern "C" void kernel_launch(void* const* d_in, const int* in_sizes, int n_in,
                              void* d_out, int out_size, void* d_ws, size_t ws_size,
                              hipStream_t stream)
{
  const float* query = (const float*)d_in[0];
  const float* keyva = (const float*)d_in[1];
  const float* Wq = (const float*)d_in[2];
  const float* bq = (const float*)d_in[3];
  const float* Wk = (const float*)d_in[4];
  const float* bk = (const float*)d_in[5];
  const float* Wv = (const float*)d_in[6];
  const float* bv = (const float*)d_in[7];
  const float* Wo = (const float*)d_in[8];
  const float* bo = (const float*)d_in[9];
  float* out = (float*)d_out;

  // workspace layout (floats): Q | K | V | AO  — 36 MB total
  float* ws = (float*)d_ws;
  float* Q  = ws;                            // 2048*256
  float* K  = Q + (size_t)B_ * S_ * D_;      // 16384*256
  float* V  = K + (size_t)B_ * HW_ * D_;     // 16384*256
  float* AO = V + (size_t)B_ * HW_ * D_;     // 2048*256

  const dim3 blk(256);
  gemm_bias<false><<<dim3((B_*S_)/64,  D_/64), blk, 0, stream>>>(query, Wq, bq, Q,  B_*S_,  D_, D_);
  gemm_bias<true ><<<dim3((B_*HW_)/64, D_/64), blk, 0, stream>>>(keyva, Wk, bk, K,  B_*HW_, D_, D_);
  gemm_bias<true ><<<dim3((B_*HW_)/64, D_/64), blk, 0, stream>>>(keyva, Wv, bv, V,  B_*HW_, D_, D_);
  attn_fused<<<dim3(B_ * NH_ * (S_/64)), blk, 0, stream>>>(Q, K, V, AO);
  gemm_bias<false><<<dim3((B_*S_)/64,  D_/64), blk, 0, stream>>>(AO, Wo, bo, out, B_*S_, D_, D_);
}